// Round 1
// baseline (635.475 us; speedup 1.0000x reference)
//
#include <hip/hip_runtime.h>

typedef unsigned short u16;
typedef __attribute__((ext_vector_type(8))) short bf16x8;
typedef __attribute__((ext_vector_type(4))) float f32x4;

#define L_ 512
#define D_ 128
#define LL_ (512*512)
#define LP_ 136   // LDS pitch for 128-wide rows (16B-aligned)
#define TP_ 72    // LDS pitch for 64-wide rows

// workspace (u16 elements): wt | a_t | b_tt | k_t  = 192.18 MiB total
#define WT_OFF 0
#define AT_OFF 98304
#define BT_OFF (AT_OFF + 128*LL_)
#define KT_OFF (BT_OFF + 128*LL_)

union U16x8 { uint4 u4; bf16x8 v; u16 s[8]; };

__device__ __forceinline__ u16 f2bf(float f){
  union { float f; unsigned int i; } w; w.f = f;
  unsigned int r = w.i + 0x7FFFu + ((w.i >> 16) & 1u);  // RNE
  return (u16)(r >> 16);
}
__device__ __forceinline__ float sigm(float x){
  return 1.0f / (1.0f + __expf(-x));
}

// transpose six 128x128 f32 weights to bf16: wt[w][n][k] = W_w[k][n]
__global__ __launch_bounds__(256) void conv_kernel(
    const float* __restrict__ Wga, const float* __restrict__ Wla,
    const float* __restrict__ Wgb, const float* __restrict__ Wlb,
    const float* __restrict__ Wgo, const float* __restrict__ Wlo,
    u16* __restrict__ wt)
{
  int idx = blockIdx.x*256 + threadIdx.x;            // 0..98303
  int w = idx >> 14, rem = idx & 16383, n = rem >> 7, k = rem & 127;
  const float* src;
  switch (w){
    case 0: src = Wga; break; case 1: src = Wla; break; case 2: src = Wgb; break;
    case 3: src = Wlb; break; case 4: src = Wgo; break; default: src = Wlo;
  }
  wt[idx] = f2bf(src[k*128 + n]);
}

// C[128x128] += A_lds[128xK=128 (pitch LP_)] * B  (wtm is [N=128][K=128] bf16)
__device__ __forceinline__ void gemm128(const u16* znlds, const u16* __restrict__ wtm,
                                        int wm, int wn, int quad, int l16, f32x4 acc[4][4])
{
  bf16x8 bf[4][4];
#pragma unroll
  for (int nt = 0; nt < 4; ++nt){
    int n = wn*64 + nt*16 + l16;
#pragma unroll
    for (int kc = 0; kc < 4; ++kc){
      U16x8 u; u.u4 = *(const uint4*)(wtm + n*128 + kc*32 + quad*8);
      bf[nt][kc] = u.v;
    }
  }
#pragma unroll
  for (int mt = 0; mt < 4; ++mt){
    int row = wm*64 + mt*16 + l16;
    bf16x8 af[4];
#pragma unroll
    for (int kc = 0; kc < 4; ++kc)
      af[kc] = *(const bf16x8*)(znlds + row*LP_ + kc*32 + quad*8);
#pragma unroll
    for (int nt = 0; nt < 4; ++nt)
#pragma unroll
      for (int kc = 0; kc < 4; ++kc)
        acc[mt][nt] = __builtin_amdgcn_mfma_f32_16x16x32_bf16(af[kc], bf[nt][kc], acc[mt][nt], 0, 0, 0);
  }
}

// 64-row variant: C[64x128] += A_lds[64x128 (pitch LP_)] * B
__device__ __forceinline__ void gemm64(const u16* alds, const u16* __restrict__ wtm,
                                       int wm, int wn, int quad, int l16, f32x4 acc[2][4])
{
  bf16x8 bf[4][4];
#pragma unroll
  for (int nt = 0; nt < 4; ++nt){
    int n = wn*64 + nt*16 + l16;
#pragma unroll
    for (int kc = 0; kc < 4; ++kc){
      U16x8 u; u.u4 = *(const uint4*)(wtm + n*128 + kc*32 + quad*8);
      bf[nt][kc] = u.v;
    }
  }
#pragma unroll
  for (int mt = 0; mt < 2; ++mt){
    int row = wm*32 + mt*16 + l16;
    bf16x8 af[4];
#pragma unroll
    for (int kc = 0; kc < 4; ++kc)
      af[kc] = *(const bf16x8*)(alds + row*LP_ + kc*32 + quad*8);
#pragma unroll
    for (int nt = 0; nt < 4; ++nt)
#pragma unroll
      for (int kc = 0; kc < 4; ++kc)
        acc[mt][nt] = __builtin_amdgcn_mfma_f32_16x16x32_bf16(af[kc], bf[nt][kc], acc[mt][nt], 0, 0, 0);
  }
}

// type0 blocks (bid<2048): row tiles (fixed i)   -> a_t[c][i][m]
// type1 blocks:            column tiles (fixed j) -> b_tt[c][j][m]
__global__ __launch_bounds__(256) void stageA_kernel(
    const float* __restrict__ z, const float* __restrict__ lnw, const float* __restrict__ lnb,
    const u16* __restrict__ wt,
    const float* __restrict__ bga, const float* __restrict__ bla,
    const float* __restrict__ bgb, const float* __restrict__ blb,
    u16* __restrict__ a_t, u16* __restrict__ b_tt)
{
  __shared__ __align__(16) u16 zn[128*LP_];
  __shared__ __align__(16) u16 trh[9216];   // [128 ch][TP_]

  const int bid = blockIdx.x;
  const int type = bid >> 11;
  const int tile = bid & 2047;
  const int outer = tile >> 2;   // i (type0) or j (type1)
  const int seg = tile & 3;

  const int t = threadIdx.x;
  const int r = t >> 1, h = t & 1;
  const int lane = t & 63, wave = t >> 6;
  const int quad = lane >> 4, l16 = lane & 15;
  const int wm = wave & 1, wn = wave >> 1;

  { // ---- LayerNorm (f32) of 128 z-rows into zn LDS (bf16) ----
    int gpos = (type == 0) ? (outer*L_ + seg*128 + r) : ((seg*128 + r)*L_ + outer);
    const float* zrow = z + gpos*D_ + h*64;
    float raw[64];
    float sum = 0.f, sq = 0.f;
#pragma unroll
    for (int q = 0; q < 16; ++q){
      float4 v = *(const float4*)(zrow + q*4);
      raw[q*4+0] = v.x; raw[q*4+1] = v.y; raw[q*4+2] = v.z; raw[q*4+3] = v.w;
      sum += v.x + v.y + v.z + v.w;
      sq  += v.x*v.x + v.y*v.y + v.z*v.z + v.w*v.w;
    }
    sum += __shfl_xor(sum, 1, 64);
    sq  += __shfl_xor(sq , 1, 64);
    float mu = sum * (1.f/128.f);
    float rstd = rsqrtf(sq*(1.f/128.f) - mu*mu + 1e-5f);
#pragma unroll
    for (int q = 0; q < 8; ++q){
      U16x8 o;
#pragma unroll
      for (int e = 0; e < 8; ++e){
        int d = h*64 + q*8 + e;
        o.s[e] = f2bf((raw[q*8+e] - mu)*rstd*lnw[d] + lnb[d]);
      }
      *(uint4*)(zn + r*LP_ + h*64 + q*8) = o.u4;
    }
  }
  __syncthreads();

  const u16* wg   = wt + (type ? 2 : 0)*16384;
  const u16* wl   = wt + (type ? 3 : 1)*16384;
  const float* bgp = type ? bgb : bga;
  const float* blp = type ? blb : bla;
  const f32x4 z4 = {0.f, 0.f, 0.f, 0.f};

  f32x4 accG[4][4], accL[4][4];
#pragma unroll
  for (int mt = 0; mt < 4; ++mt)
#pragma unroll
    for (int nt = 0; nt < 4; ++nt){ accG[mt][nt] = z4; accL[mt][nt] = z4; }

  gemm128(zn, wg, wm, wn, quad, l16, accG);
#pragma unroll
  for (int nt = 0; nt < 4; ++nt){
    float bb = bgp[wn*64 + nt*16 + l16];
#pragma unroll
    for (int mt = 0; mt < 4; ++mt)
#pragma unroll
      for (int e = 0; e < 4; ++e)
        accG[mt][nt][e] = sigm(accG[mt][nt][e] + bb);
  }
  gemm128(zn, wl, wm, wn, quad, l16, accL);
#pragma unroll
  for (int nt = 0; nt < 4; ++nt){
    float bb = blp[wn*64 + nt*16 + l16];
#pragma unroll
    for (int mt = 0; mt < 4; ++mt)
#pragma unroll
      for (int e = 0; e < 4; ++e)
        accG[mt][nt][e] *= (accL[mt][nt][e] + bb);   // gated product in accG
  }

  // ---- transpose-store product channel-major (wave-row split, 2 passes) ----
  u16* dst = type ? b_tt : a_t;
  const int base = outer*L_ + seg*128;
#pragma unroll
  for (int pass = 0; pass < 2; ++pass){
    if (wm == pass){
#pragma unroll
      for (int nt = 0; nt < 4; ++nt){
        int gcol = wn*64 + nt*16 + l16;
#pragma unroll
        for (int mt = 0; mt < 4; ++mt)
#pragma unroll
          for (int e = 0; e < 4; ++e)
            trh[gcol*TP_ + mt*16 + quad*4 + e] = f2bf(accG[mt][nt][e]);
      }
    }
    __syncthreads();
#pragma unroll
    for (int q = 0; q < 4; ++q){
      uint4 v = *(const uint4*)(trh + r*TP_ + h*32 + q*8);
      *(uint4*)(dst + r*LL_ + base + pass*64 + h*32 + q*8) = v;
    }
    __syncthreads();
  }
}

// k_t[c][i][j] = sum_m a_t[c][i][m] * b_tt[c][j][m]
// NEW: global_load_lds width-16 staging (linear LDS dest, pre-swizzled global src,
// XOR-swizzled ds_read) + double-buffered K-tiles with counted vmcnt + raw s_barrier.
__global__ __launch_bounds__(256) void stageT_kernel(
    const u16* __restrict__ a_t, const u16* __restrict__ b_tt, u16* __restrict__ k_t)
{
  __shared__ __align__(16) u16 As[2][128*64];   // 32 KiB
  __shared__ __align__(16) u16 Bs[2][128*64];   // 32 KiB
  const int c = blockIdx.y;
  const int it = blockIdx.x >> 2, jt = blockIdx.x & 3;
  const u16* Ab = a_t + c*LL_ + it*128*L_;
  const u16* Bb = b_tt + c*LL_ + jt*128*L_;
  const int t = threadIdx.x;
  const int lane = t & 63, wave = t >> 6;
  const int quad = lane >> 4, l16 = lane & 15;
  const int wm = wave & 1, wn = wave >> 1;
  const int sr8 = lane >> 3, scl = lane & 7;
  const int cgx = scl ^ sr8;                  // pre-swizzled source chunk (row&7 == sr8)
  const int swz = (l16 & 7) << 3;             // read-side XOR in u16 units (row&7 == l16&7)

  f32x4 acc[4][4];
  const f32x4 z4 = {0.f,0.f,0.f,0.f};
#pragma unroll
  for (int mt = 0; mt < 4; ++mt)
#pragma unroll
    for (int nt = 0; nt < 4; ++nt) acc[mt][nt] = z4;

  // stage one 128x64 K-tile of A and B into buffer b.
  // LDS[row][cl] = G[row][cl ^ (row&7)]  (involution; read applies same XOR)
  auto stage = [&](int b, int k0){
#pragma unroll
    for (int q = 0; q < 4; ++q){
      int row = q*32 + wave*8 + sr8;
      __builtin_amdgcn_global_load_lds(
          (const __attribute__((address_space(1))) void*)(Ab + row*L_ + k0 + cgx*8),
          (__attribute__((address_space(3))) void*)(&As[b][(q*32 + wave*8)*64]),
          16, 0, 0);
    }
#pragma unroll
    for (int q = 0; q < 4; ++q){
      int row = q*32 + wave*8 + sr8;
      __builtin_amdgcn_global_load_lds(
          (const __attribute__((address_space(1))) void*)(Bb + row*L_ + k0 + cgx*8),
          (__attribute__((address_space(3))) void*)(&Bs[b][(q*32 + wave*8)*64]),
          16, 0, 0);
    }
  };

  stage(0, 0);
  for (int kt = 0; kt < 8; ++kt){
    const int cur = kt & 1;
    if (kt < 7){
      stage(cur ^ 1, (kt + 1)*64);                       // prefetch next tile (8 loads)
      asm volatile("s_waitcnt vmcnt(8)" ::: "memory");   // wait current tile only
    } else {
      asm volatile("s_waitcnt vmcnt(0)" ::: "memory");
    }
    __builtin_amdgcn_s_barrier();                        // (1) cur buffer ready for all
    asm volatile("" ::: "memory");                       // don't hoist ds_reads above
    const u16* Ac = &As[cur][0];
    const u16* Bc = &Bs[cur][0];
    bf16x8 bfr[4][2];
#pragma unroll
    for (int nt = 0; nt < 4; ++nt){
      int brow = wn*64 + nt*16 + l16;
#pragma unroll
      for (int ks = 0; ks < 2; ++ks)
        bfr[nt][ks] = *(const bf16x8*)(Bc + brow*64 + (((ks*4 + quad)*8) ^ swz));
    }
#pragma unroll
    for (int mt = 0; mt < 4; ++mt){
      int arow = wm*64 + mt*16 + l16;
      bf16x8 af[2];
#pragma unroll
      for (int ks = 0; ks < 2; ++ks)
        af[ks] = *(const bf16x8*)(Ac + arow*64 + (((ks*4 + quad)*8) ^ swz));
#pragma unroll
      for (int nt = 0; nt < 4; ++nt)
#pragma unroll
        for (int ks = 0; ks < 2; ++ks)
          acc[mt][nt] = __builtin_amdgcn_mfma_f32_16x16x32_bf16(af[ks], bfr[nt][ks], acc[mt][nt], 0, 0, 0);
    }
    asm volatile("" ::: "memory");
    __builtin_amdgcn_s_barrier();                        // (2) all reads of cur done
    asm volatile("" ::: "memory");                       // don't hoist next stage above
  }

#pragma unroll
  for (int mt = 0; mt < 4; ++mt)
#pragma unroll
    for (int nt = 0; nt < 4; ++nt){
      int gcol = wn*64 + nt*16 + l16;
#pragma unroll
      for (int e = 0; e < 4; ++e){
        int grow = wm*64 + mt*16 + quad*4 + e;
        k_t[c*LL_ + (it*128 + grow)*L_ + jt*128 + gcol] = f2bf(acc[mt][nt][e]);
      }
    }
}

// out[pos][d] = sigmoid(LN(z)[pos]@Wgo + bgo) * (LN_c(k)[pos]@Wlo + blo), f32 out
__global__ __launch_bounds__(256) void stageC_kernel(
    const u16* __restrict__ k_t, const float* __restrict__ z,
    const u16* __restrict__ wt,
    const float* __restrict__ lnw, const float* __restrict__ lnb,
    const float* __restrict__ onw, const float* __restrict__ onb,
    const float* __restrict__ bgo, const float* __restrict__ blo,
    float* __restrict__ out)
{
  __shared__ __align__(16) u16 kl[128*TP_];   // k tile [c][64 j]
  __shared__ __align__(16) u16 zn2[64*LP_];   // LN_c(k) [j][c]
  __shared__ __align__(16) u16 znp[64*LP_];   // LN(z)   [pos][c]
  const u16* wtgo = wt + 4*16384;
  const u16* wtlo = wt + 5*16384;
  const int bx = blockIdx.x;
  const int pos0 = (bx >> 3)*L_ + (bx & 7)*64;
  const int t = threadIdx.x, r = t >> 1, h = t & 1;
  const int rl4 = t >> 2, qd = t & 3;
  const int lane = t & 63, wave = t >> 6;
  const int quad = lane >> 4, l16 = lane & 15;
  const int wm = wave & 1, wn = wave >> 1;

#pragma unroll
  for (int q = 0; q < 4; ++q)
    *(uint4*)(kl + r*TP_ + h*32 + q*8) = *(const uint4*)(k_t + r*LL_ + pos0 + h*32 + q*8);
  __syncthreads();

  { // LN over channels of k for column j=rl4 (4 threads/column via qd)
    float sum = 0.f, sq = 0.f;
    float kv[32];
#pragma unroll
    for (int q = 0; q < 32; ++q){
      union { unsigned int i; float f; } w;
      w.i = ((unsigned int)kl[(qd*32 + q)*TP_ + rl4]) << 16;
      kv[q] = w.f; sum += w.f; sq += w.f*w.f;
    }
    sum += __shfl_xor(sum, 1, 64); sq += __shfl_xor(sq, 1, 64);
    sum += __shfl_xor(sum, 2, 64); sq += __shfl_xor(sq, 2, 64);
    float mu = sum*(1.f/128.f);
    float rstd = rsqrtf(sq*(1.f/128.f) - mu*mu + 1e-5f);
#pragma unroll
    for (int q = 0; q < 4; ++q){
      U16x8 o;
#pragma unroll
      for (int e = 0; e < 8; ++e){
        int cch = qd*32 + q*8 + e;
        o.s[e] = f2bf((kv[q*8+e] - mu)*rstd*onw[cch] + onb[cch]);
      }
      *(uint4*)(zn2 + rl4*LP_ + qd*32 + q*8) = o.u4;
    }
  }
  { // LN of z row pos0+rl4 (4 threads/position via qd), f32 source
    const float* zr = z + (pos0 + rl4)*D_ + qd*32;
    float zv[32];
    float sum = 0.f, sq = 0.f;
#pragma unroll
    for (int q = 0; q < 8; ++q){
      float4 v = *(const float4*)(zr + q*4);
      zv[q*4+0] = v.x; zv[q*4+1] = v.y; zv[q*4+2] = v.z; zv[q*4+3] = v.w;
      sum += v.x + v.y + v.z + v.w;
      sq  += v.x*v.x + v.y*v.y + v.z*v.z + v.w*v.w;
    }
    sum += __shfl_xor(sum, 1, 64); sq += __shfl_xor(sq, 1, 64);
    sum += __shfl_xor(sum, 2, 64); sq += __shfl_xor(sq, 2, 64);
    float mu = sum*(1.f/128.f);
    float rstd = rsqrtf(sq*(1.f/128.f) - mu*mu + 1e-5f);
#pragma unroll
    for (int q = 0; q < 4; ++q){
      U16x8 o;
#pragma unroll
      for (int e = 0; e < 8; ++e){
        int cch = qd*32 + q*8 + e;
        o.s[e] = f2bf((zv[q*8+e] - mu)*rstd*lnw[cch] + lnb[cch]);
      }
      *(uint4*)(znp + rl4*LP_ + qd*32 + q*8) = o.u4;
    }
  }
  __syncthreads();

  f32x4 accK[2][4], accO[2][4];
  const f32x4 z4 = {0.f,0.f,0.f,0.f};
#pragma unroll
  for (int mt = 0; mt < 2; ++mt)
#pragma unroll
    for (int nt = 0; nt < 4; ++nt){ accK[mt][nt] = z4; accO[mt][nt] = z4; }

  gemm64(zn2, wtlo, wm, wn, quad, l16, accK);
  gemm64(znp, wtgo, wm, wn, quad, l16, accO);

#pragma unroll
  for (int nt = 0; nt < 4; ++nt){
    int gcol = wn*64 + nt*16 + l16;
    float bo = bgo[gcol], bl = blo[gcol];
#pragma unroll
    for (int mt = 0; mt < 2; ++mt)
#pragma unroll
      for (int e = 0; e < 4; ++e){
        int grow = wm*32 + mt*16 + quad*4 + e;
        float s = sigm(accO[mt][nt][e] + bo);
        out[(pos0 + grow)*D_ + gcol] = s*(accK[mt][nt][e] + bl);
      }
  }
}

extern "C" void kernel_launch(void* const* d_in, const int* in_sizes, int n_in,
                              void* d_out, int out_size, void* d_ws, size_t ws_size,
                              hipStream_t stream)
{
  const float* z   = (const float*)d_in[0];
  const float* lnw = (const float*)d_in[1];
  const float* lnb = (const float*)d_in[2];
  const float* Wga = (const float*)d_in[3];
  const float* bga = (const float*)d_in[4];
  const float* Wla = (const float*)d_in[5];
  const float* bla = (const float*)d_in[6];
  const float* Wgb = (const float*)d_in[7];
  const float* bgb = (const float*)d_in[8];
  const float* Wlb = (const float*)d_in[9];
  const float* blb = (const float*)d_in[10];
  const float* onw = (const float*)d_in[11];
  const float* onb = (const float*)d_in[12];
  const float* Wgo = (const float*)d_in[13];
  const float* bgo = (const float*)d_in[14];
  const float* Wlo = (const float*)d_in[15];
  const float* blo = (const float*)d_in[16];

  u16* ws   = (u16*)d_ws;
  u16* wt   = ws + WT_OFF;
  u16* a_t  = ws + AT_OFF;
  u16* b_tt = ws + BT_OFF;
  u16* k_t  = ws + KT_OFF;
  float* out = (float*)d_out;

  conv_kernel<<<384, 256, 0, stream>>>(Wga, Wla, Wgb, Wlb, Wgo, Wlo, wt);
  stageA_kernel<<<4096, 256, 0, stream>>>(z, lnw, lnb, wt, bga, bla, bgb, blb, a_t, b_tt);
  stageT_kernel<<<dim3(16, 128), 256, 0, stream>>>(a_t, b_tt, k_t);
  stageC_kernel<<<4096, 256, 0, stream>>>(k_t, z, wt, lnw, lnb, onw, onb, bgo, blo, out);
}